// Round 6
// baseline (659.366 us; speedup 1.0000x reference)
//
#include <hip/hip_runtime.h>
#include <hip/hip_cooperative_groups.h>

namespace cg = cooperative_groups;

#define NNODES 8192
#define NEDGES 16384
#define DD 128
#define RR 64
#define BB 16

typedef __attribute__((ext_vector_type(8))) short bf16x8;
typedef __attribute__((ext_vector_type(4))) float f32x4;

// ---- ws layout, offsets in 4-byte words ----
#define FWB_OFF   0                 // bf16 fwbT[64][128][128] (n-major, k-contig)
#define INPB_OFF  524288            // bf16 inp_b[8192][128]
#define SWB_OFF   1048576           // bf16 swb[128][128]
#define Y_OFF     1056768           // f32 Y[16384][128], indexed by target-sorted pos
#define RH_OFF    3153920           // int relHist[64]
#define TH_OFF    3153984           // int tgtHist[8192]   (contiguous after RH)
#define CR_OFF    3162176           // int relCursor[64]
#define CT_OFF    3162240           // int tgtCursor[8192]
#define NT_OFF    3170432           // int ntiles
#define TOFF_OFF  3170433           // int tgtOff[8192]
#define POS_OFF   3178625           // int posT[e]
#define RELT_OFF  3195009           // int rel per target-sorted slot
#define SORTR_OFF 3211393           // int relation-sorted edge ids
#define TILE_OFF  3227777           // int tile[1088][3] = (rel, base, cnt)

static __device__ __forceinline__ unsigned short f2bf(float f) {
  union { float f; unsigned u; } v; v.f = f;
  unsigned r = v.u + 0x7FFFu + ((v.u >> 16) & 1u);   // RNE
  return (unsigned short)(r >> 16);
}

// ONE cooperative kernel: grid = 1024 blocks x 256 threads (4 blocks/CU).
__global__ __launch_bounds__(256, 4) void mega_kernel(
    const float* __restrict__ inp, const int* __restrict__ deprel,
    const int* __restrict__ edge_index, const float* __restrict__ weight,
    const float* __restrict__ w_comp, const float* __restrict__ self_w,
    const float* __restrict__ bias, float* __restrict__ ws_f,
    float* __restrict__ out) {
  cg::grid_group grid = cg::this_grid();
  int* wsi = (int*)ws_f;
  const int b = blockIdx.x, t = threadIdx.x;
  __shared__ float fl[32][33];
  __shared__ int part[256];

  // ---- phase 0: zero histograms (RH + TH contiguous: 8256 ints) ----
  {
    int idx = b * 256 + t;
    if (idx < 64 + NNODES) wsi[RH_OFF + idx] = 0;
  }
  grid.sync();

  // ---- phase 1: fw combine+transpose+cast (tile b), inp cast, swb, hist ----
  {
    const int r = b >> 4, tile = b & 15;
    const int k0 = (tile >> 2) * 32, n0 = (tile & 3) * 32;
    const int kl = t >> 3, nl4 = (t & 7) * 4;
    const float* wc = w_comp + r * BB;
    float4 acc = {0.f, 0.f, 0.f, 0.f};
#pragma unroll
    for (int bb = 0; bb < BB; ++bb) {
      float c = wc[bb];
      float4 w = *(const float4*)(weight + bb * DD * DD + (k0 + kl) * DD + n0 + nl4);
      acc.x += c * w.x; acc.y += c * w.y; acc.z += c * w.z; acc.w += c * w.w;
    }
    fl[nl4 + 0][kl] = acc.x; fl[nl4 + 1][kl] = acc.y;
    fl[nl4 + 2][kl] = acc.z; fl[nl4 + 3][kl] = acc.w;
    __syncthreads();
    const int nl = t >> 3, kq = (t & 7) * 4;
    unsigned short* dst = (unsigned short*)(ws_f + FWB_OFF) + r * DD * DD + (n0 + nl) * DD + k0 + kq;
    *(ushort4*)dst = make_ushort4(f2bf(fl[nl][kq + 0]), f2bf(fl[nl][kq + 1]),
                                  f2bf(fl[nl][kq + 2]), f2bf(fl[nl][kq + 3]));
  }
  {
    int idx = b * 1024 + t * 4;          // 1024 blocks cover all 1,048,576 elems
    float4 v = *(const float4*)(inp + idx);
    unsigned short* dst = (unsigned short*)(ws_f + INPB_OFF) + idx;
    *(ushort4*)dst = make_ushort4(f2bf(v.x), f2bf(v.y), f2bf(v.z), f2bf(v.w));
  }
  if (b < 16) {
    int idx = b * 1024 + t * 4;
    float4 v = *(const float4*)(self_w + idx);
    unsigned short* dst = (unsigned short*)(ws_f + SWB_OFF) + idx;
    *(ushort4*)dst = make_ushort4(f2bf(v.x), f2bf(v.y), f2bf(v.z), f2bf(v.w));
  }
  if (b < 64) {
    int e = b * 256 + t;
    int rel = deprel[e];
    int tgt = edge_index[NEDGES + e];
    atomicAdd(wsi + RH_OFF + rel, 1);
    atomicAdd(wsi + TH_OFF + tgt, 1);
  }
  grid.sync();

  // ---- phase 2: plan (block 0 only): target CSR + relation scan + tiles ----
  if (b == 0) {
    const int base = t * 32;
    int s = 0;
#pragma unroll
    for (int k = 0; k < 32; ++k) s += wsi[TH_OFF + base + k];
    part[t] = s;
    __syncthreads();
    if (t < 64) {   // wave 0: exclusive scan of 256 partials, 4 per lane
      int p0 = part[4 * t], p1 = part[4 * t + 1], p2 = part[4 * t + 2], p3 = part[4 * t + 3];
      int sum4 = p0 + p1 + p2 + p3;
      int inc = sum4;
#pragma unroll
      for (int d = 1; d < 64; d <<= 1) {
        int v = __shfl_up(inc, d, 64);
        if (t >= d) inc += v;
      }
      int excl = inc - sum4;
      part[4 * t] = excl;
      part[4 * t + 1] = excl + p0;
      part[4 * t + 2] = excl + p0 + p1;
      part[4 * t + 3] = excl + p0 + p1 + p2;
    }
    __syncthreads();
    int run = part[t];
    for (int k = 0; k < 32; ++k) {
      int v = wsi[TH_OFF + base + k];
      wsi[TOFF_OFF + base + k] = run;
      wsi[CT_OFF + base + k] = run;
      run += v;
    }
    if (t < 64) {   // wave 0: relation scan + tile table
      int n = wsi[RH_OFF + t];
      int nt = (n + 15) >> 4;
      int ei = n, ti = nt;
#pragma unroll
      for (int d = 1; d < 64; d <<= 1) {
        int e2 = __shfl_up(ei, d, 64);
        int t2 = __shfl_up(ti, d, 64);
        if (t >= d) { ei += e2; ti += t2; }
      }
      int e0 = ei - n, t0 = ti - nt;
      wsi[CR_OFF + t] = e0;
      for (int k = 0; k < nt; ++k) {
        int* te = wsi + TILE_OFF + (t0 + k) * 3;
        te[0] = t; te[1] = e0 + k * 16; te[2] = min(16, n - k * 16);
      }
      if (t == 63) wsi[NT_OFF] = ti;
    }
  }
  grid.sync();

  // ---- phase 3: scatter (blocks 0-63) ----
  if (b < 64) {
    int e = b * 256 + t;
    int rel = deprel[e];
    int tgt = edge_index[NEDGES + e];
    int pR = atomicAdd(wsi + CR_OFF + rel, 1);
    wsi[SORTR_OFF + pR] = e;
    int pT = atomicAdd(wsi + CT_OFF + tgt, 1);
    wsi[POS_OFF + e] = pT;
    wsi[RELT_OFF + pT] = rel;
  }
  grid.sync();

  // ---- phase 4: gemm. 4096 wave-slots: [0,1024) self halves -> out,
  //      [1024, 1024+2*NT) edge halves -> Y ----
  {
    const int lane = t & 63;
    const int wave = b * 4 + (t >> 6);
    const int ln = lane & 15, q = lane >> 4;
    const unsigned short* inpb = (const unsigned short*)(ws_f + INPB_OFF);
    if (wave < 1024) {
      const int m0 = (wave >> 1) * 16;
      const int h = wave & 1;
      const unsigned short* arow = inpb + (m0 + ln) * DD;
      bf16x8 a[4];
#pragma unroll
      for (int kk = 0; kk < 4; ++kk)
        a[kk] = *(const bf16x8*)(arow + kk * 32 + q * 8);
      const unsigned short* swb = (const unsigned short*)(ws_f + SWB_OFF);
#pragma unroll
      for (int ntb = 0; ntb < 4; ++ntb) {
        const int n0 = (h * 4 + ntb) * 16;
        f32x4 acc = {0.f, 0.f, 0.f, 0.f};
        const unsigned short* brow = swb + (n0 + ln) * DD + q * 8;
#pragma unroll
        for (int kk = 0; kk < 4; ++kk) {
          bf16x8 bv = *(const bf16x8*)(brow + kk * 32);
          acc = __builtin_amdgcn_mfma_f32_16x16x32_bf16(a[kk], bv, acc, 0, 0, 0);
        }
        float bvs = bias[n0 + ln];
#pragma unroll
        for (int v = 0; v < 4; ++v)
          out[(m0 + q * 4 + v) * DD + n0 + ln] = acc[v] + bvs;
      }
    } else {
      const int w2 = wave - 1024;
      const int et = w2 >> 1, h = w2 & 1;
      if (et < wsi[NT_OFF]) {
        const int* te = wsi + TILE_OFF + et * 3;
        const int rel = te[0], base = te[1], cnt = te[2];
        const int e_m = wsi[SORTR_OFF + base + min(ln, cnt - 1)];
        const int s_m = edge_index[e_m];
        const int p_m = wsi[POS_OFF + e_m];
        bf16x8 a[4];
        const unsigned short* arow = inpb + s_m * DD;
#pragma unroll
        for (int kk = 0; kk < 4; ++kk)
          a[kk] = *(const bf16x8*)(arow + kk * 32 + q * 8);
        int pv[4];
#pragma unroll
        for (int v = 0; v < 4; ++v)
          pv[v] = __shfl(p_m, q * 4 + v);
        const unsigned short* fwb = (const unsigned short*)(ws_f + FWB_OFF) + rel * DD * DD;
        float* Yf = ws_f + Y_OFF;
#pragma unroll
        for (int ntb = 0; ntb < 4; ++ntb) {
          const int n0 = (h * 4 + ntb) * 16;
          f32x4 acc = {0.f, 0.f, 0.f, 0.f};
          const unsigned short* brow = fwb + (n0 + ln) * DD + q * 8;
#pragma unroll
          for (int kk = 0; kk < 4; ++kk) {
            bf16x8 bv = *(const bf16x8*)(brow + kk * 32);
            acc = __builtin_amdgcn_mfma_f32_16x16x32_bf16(a[kk], bv, acc, 0, 0, 0);
          }
#pragma unroll
          for (int v = 0; v < 4; ++v) {
            int m = q * 4 + v;
            if (m < cnt) Yf[pv[v] * DD + n0 + ln] = acc[v];
          }
        }
      }
    }
  }
  grid.sync();

  // ---- phase 5: reduce. thread = (node, col4) ----
  {
    const int tg = b * 256 + t;
    const int node = tg >> 5, c = (tg & 31) * 4;
    const int off = wsi[TOFF_OFF + node];
    const int ne = wsi[TH_OFF + node];
    float4 acc = *(float4*)(out + node * DD + c);
    const float* Yf = ws_f + Y_OFF;
    const int* relt = wsi + RELT_OFF + off;
    for (int j = 0; j < ne; ++j) {
      int rj = relt[j];
      int cj = 0;
      for (int k = 0; k < ne; ++k) cj += (relt[k] == rj) ? 1 : 0;
      float inv = 1.0f / (float)cj;
      float4 y = *(const float4*)(Yf + (off + j) * DD + c);
      acc.x += y.x * inv; acc.y += y.y * inv; acc.z += y.z * inv; acc.w += y.w * inv;
    }
    *(float4*)(out + node * DD + c) = acc;
  }
}

extern "C" void kernel_launch(void* const* d_in, const int* in_sizes, int n_in,
                              void* d_out, int out_size, void* d_ws, size_t ws_size,
                              hipStream_t stream) {
  const float* inp        = (const float*)d_in[0];
  const int*   deprel     = (const int*)d_in[1];
  const int*   edge_index = (const int*)d_in[2];
  const float* weight     = (const float*)d_in[3];
  const float* w_comp     = (const float*)d_in[4];
  const float* self_w     = (const float*)d_in[5];
  const float* bias       = (const float*)d_in[6];
  float* out = (float*)d_out;
  float* ws  = (float*)d_ws;

  void* args[] = {(void*)&inp, (void*)&deprel, (void*)&edge_index, (void*)&weight,
                  (void*)&w_comp, (void*)&self_w, (void*)&bias, (void*)&ws, (void*)&out};
  hipLaunchCooperativeKernel((void*)mega_kernel, dim3(1024), dim3(256), args, 0, stream);
}